// Round 12
// baseline (50.376 us; speedup 1.0000x reference)
//
#include <hip/hip_runtime.h>
#include <math.h>

#define BB   8
#define NHD  8
#define SSZ  1024
#define CIN  256
#define HIDC 256

typedef __bf16 bf16_t;
typedef bf16_t bf16x8 __attribute__((ext_vector_type(8)));
typedef float  f32x4v __attribute__((ext_vector_type(4)));

typedef __attribute__((address_space(3))) unsigned short as3_u16;
typedef __attribute__((address_space(1))) unsigned short as1_u16;

__device__ inline unsigned cvt_pk_bf16(float lo, float hi) {
    unsigned r;
    asm("v_cvt_pk_bf16_f32 %0, %1, %2" : "=v"(r) : "v"(lo), "v"(hi));
    return r;
}
__device__ inline unsigned short f2bf(float f) {
    unsigned u = __builtin_bit_cast(unsigned, f);
    u = (u + 0x7fffu + ((u >> 16) & 1u)) >> 16;   // RNE
    return (unsigned short)u;
}
__device__ inline float exp2_fast(float x) {
    float r;
    asm("v_exp_f32 %0, %1" : "=v"(r) : "v"(x));
    return r;
}
__device__ inline int kmap5(int i) {
    return ((i >> 2) & 3) * 8 + ((i >> 4) & 1) * 4 + (i & 3);
}

// ---------------------------------------------------------------------------
// Fused QKV GEMM, BM=96 (one head per block, 512 blocks = 2/CU balanced),
// now with T14 async-STAGE split: half-1 global loads are issued into
// REGISTERS before half-0 compute (HBM/L2 latency hides under 48 MFMAs),
// cvt+ds_write happen after the barrier. Same barrier count as round 10.
// blockIdx.y==8 blocks convert w_out f32->bf16 instead.
// ---------------------------------------------------------------------------
#define QKV_LDS_LOAD(WF, XF, KB)                                                    \
    {                                                                               \
        _Pragma("unroll") for (int df = 0; df < 3; ++df) {                          \
            const int orow = (w >> 1) * 48 + df * 16 + ln;                          \
            WF[df] = *(const bf16x8*)(Ws + orow * 128 + ((((KB) + g) ^ (orow & 15)) << 3)); \
        }                                                                           \
        _Pragma("unroll") for (int sf = 0; sf < 4; ++sf) {                          \
            const int srow = sbl + sf * 16 + ln;                                    \
            XF[sf] = *(const bf16x8*)(Xs + srow * 128 + ((((KB) + g) ^ (srow & 15)) << 3)); \
        }                                                                           \
    }
#define QKV_MMA(WF, XF)                                                             \
    {                                                                               \
        _Pragma("unroll") for (int df = 0; df < 3; ++df)                            \
            _Pragma("unroll") for (int sf = 0; sf < 4; ++sf)                        \
                acc[df][sf] = __builtin_amdgcn_mfma_f32_16x16x32_bf16(WF[df], XF[sf], acc[df][sf], 0, 0, 0); \
    }

__global__ __launch_bounds__(256, 2) void qkv_fused(
    const float* __restrict__ W, const float* __restrict__ x,
    const float* __restrict__ w_out, const float* __restrict__ bias,
    unsigned short* __restrict__ qkT, unsigned short* __restrict__ v_buf,
    unsigned short* __restrict__ Wo)
{
    __shared__ unsigned short Ws[96 * 128];    // [o_loc][c_half], swizzled, 24 KB
    __shared__ unsigned short Xs[128 * 128];   // [s_loc][c_half], swizzled, 32 KB

    const int tid = threadIdx.x;

    if (blockIdx.y == 8) {                     // w_out f32 -> bf16 (64 blocks)
        const int chunk = blockIdx.z * 8 + blockIdx.x;        // 0..63
        const size_t idx = (size_t)chunk * 1024 + (size_t)tid * 4;
        float4 v = *(const float4*)(w_out + idx);
        ushort4 pk;
        pk.x = f2bf(v.x); pk.y = f2bf(v.y); pk.z = f2bf(v.z); pk.w = f2bf(v.w);
        *(ushort4*)(Wo + idx) = pk;
        return;
    }

    const int l = tid & 63, w = tid >> 6;
    const int g = l >> 4, ln = l & 15;
    const int b  = blockIdx.z;
    const int head = blockIdx.y;               // one head per block
    const int o0 = head * 96;
    const int ob = o0 + (w >> 1) * 48;
    const int s0 = blockIdx.x * 128;
    const int sbl = (w & 1) * 64;
    const int bh  = b * NHD + head;

    // ---- T14 staging helpers: load to regs / write regs to LDS ----
    f32x4v wbuf[12];        // W half: 96x128 f32 / 256 thr = 12 float4
    f32x4v xbuf[8][2];      // x half: 128x128 f32 / 256 thr = 8 row-pairs

    auto load_w = [&](int h) {
        #pragma unroll
        for (int it = 0; it < 12; ++it) {
            const int u = it * 256 + tid;
            const int row = u >> 5, cq = u & 31;
            wbuf[it] = *(const f32x4v*)(W + (size_t)(o0 + row) * 256 + h * 128 + cq * 4);
        }
    };
    auto write_w = [&]() {
        #pragma unroll
        for (int it = 0; it < 12; ++it) {
            const int u = it * 256 + tid;
            const int row = u >> 5, cq = u & 31;
            const int c_loc = cq * 4;
            const int cbp = ((c_loc >> 3) ^ (row & 15)) << 3;
            unsigned two[2] = { cvt_pk_bf16(wbuf[it][0], wbuf[it][1]),
                                cvt_pk_bf16(wbuf[it][2], wbuf[it][3]) };
            *(uint2*)(Ws + row * 128 + cbp + (c_loc & 7)) = *(uint2*)two;
        }
    };
    auto load_x = [&](int h) {
        #pragma unroll
        for (int it = 0; it < 8; ++it) {
            const int u = it * 256 + tid;
            const int cp = u >> 5, sq = u & 31;
            const float* r0 = x + ((size_t)b * CIN + h * 128 + 2 * cp) * SSZ + s0 + sq * 4;
            xbuf[it][0] = *(const f32x4v*)r0;
            xbuf[it][1] = *(const f32x4v*)(r0 + SSZ);
        }
    };
    auto write_x = [&]() {
        #pragma unroll
        for (int it = 0; it < 8; ++it) {
            const int u = it * 256 + tid;
            const int cp = u >> 5, sq = u & 31;
            const int c_loc = 2 * cp, cb = c_loc >> 3;
            #pragma unroll
            for (int j = 0; j < 4; ++j) {
                const int s_loc = sq * 4 + j;
                const int elem = s_loc * 128 + ((cb ^ (s_loc & 15)) << 3) + (c_loc & 7);
                *(unsigned*)(Xs + elem) = cvt_pk_bf16(xbuf[it][0][j], xbuf[it][1][j]);
            }
        }
    };

    f32x4v acc[3][4];
    const f32x4v zero4 = {0.f, 0.f, 0.f, 0.f};
    #pragma unroll
    for (int df = 0; df < 3; ++df)
        #pragma unroll
        for (int sf = 0; sf < 4; ++sf) acc[df][sf] = zero4;

    bf16x8 wA[3], xA[4], wB[3], xB[4];

    // half 0: load + write + barrier
    load_w(0); load_x(0);
    write_w(); write_x();
    __syncthreads();

    // issue half-1 loads NOW (latency hides under half-0 compute)
    load_w(1); load_x(1);

    // compute half 0
    QKV_LDS_LOAD(wA, xA, 0);
    QKV_LDS_LOAD(wB, xB, 4);
    QKV_MMA(wA, xA);
    QKV_LDS_LOAD(wA, xA, 8);
    QKV_MMA(wB, xB);
    QKV_LDS_LOAD(wB, xB, 12);
    QKV_MMA(wA, xA);
    QKV_MMA(wB, xB);

    __syncthreads();                           // all half-0 LDS reads done
    write_w(); write_x();                      // waits on in-flight loads here
    __syncthreads();                           // staging visible

    // compute half 1
    QKV_LDS_LOAD(wA, xA, 0);
    QKV_LDS_LOAD(wB, xB, 4);
    QKV_MMA(wA, xA);
    QKV_LDS_LOAD(wA, xA, 8);
    QKV_MMA(wB, xB);
    QKV_LDS_LOAD(wB, xB, 12);
    QKV_MMA(wA, xA);
    QKV_MMA(wB, xB);

    #pragma unroll
    for (int df = 0; df < 3; ++df) {
        const int o16  = ob + df * 16;         // stays within one 32-ch part
        const int part = (o16 >> 5) % 3;       // 0=q 1=k 2=v
        const float4 b4 = *(const float4*)(bias + o16 + g * 4);
        const float bias_r[4] = {b4.x, b4.y, b4.z, b4.w};
        const int chb = (o16 & 31) + g * 4;

        float vals[4][4];
        #pragma unroll
        for (int sf = 0; sf < 4; ++sf)
            #pragma unroll
            for (int r = 0; r < 4; ++r) {
                float z = acc[df][sf][r] + bias_r[r];
                z = z / (1.f + __expf(-z));                  // SiLU
                if (part == 0) z *= 0.25503482107810536f;    // log2e/sqrt(32)
                vals[sf][r] = z;
            }

        if (part < 2) {
            const int slotb = ((chb >> 2) & 3) * 8 + ((chb >> 4) & 1) * 4;
            #pragma unroll
            for (int sf = 0; sf < 4; ++sf) {
                const int key = s0 + sbl + sf * 16 + ln;
                ushort4 pk;
                pk.x = f2bf(vals[sf][0]); pk.y = f2bf(vals[sf][1]);
                pk.z = f2bf(vals[sf][2]); pk.w = f2bf(vals[sf][3]);
                *(ushort4*)(qkT + ((size_t)bh << 16) + (size_t)key * 64 + part * 32 + slotb) = pk;
            }
        } else {
            #pragma unroll
            for (int sf = 0; sf < 4; ++sf) {
                const int key  = s0 + sbl + sf * 16 + ln;
                const int koff = (key & ~31) + kmap5(key & 31);
                #pragma unroll
                for (int r = 0; r < 4; ++r)
                    v_buf[((size_t)bh << 15) + ((size_t)(chb + r) << 10) + koff] = f2bf(vals[sf][r]);
            }
        }
    }
}

// ---------------------------------------------------------------------------
// MFMA flash attention, no-max exact softmax, 16 q-rows/wave for 4 waves/SIMD
// occupancy (round-10 version, verbatim — split-K variant measured neutral).
// 4-buffer LDS pipeline, 2 tiles ahead, one barrier per tile, counted
// vmcnt(4). Grid (64 bh, 16 qt).
// ---------------------------------------------------------------------------
__global__ __launch_bounds__(256) void attn_mfma(
    const unsigned short* __restrict__ qkT,
    const unsigned short* __restrict__ v_buf,
    unsigned short* __restrict__ At)
{
    __shared__ unsigned short Ksh[4][2048];
    __shared__ unsigned short Vsh[4][2048];

    const int tid = threadIdx.x;
    const int l   = tid & 63;
    const int w   = tid >> 6;
    const int g   = l >> 4;
    const int ln  = l & 15;
    const int bh  = blockIdx.x;
    const int qt  = blockIdx.y;          // 0..15

    const unsigned short* qkrow = qkT   + ((size_t)bh << 16);
    const unsigned short* vb    = v_buf + ((size_t)bh << 15);

    const int q0 = qt * 64 + w * 16;

    const bf16x8 qf_ = *(const bf16x8*)(qkrow + (size_t)(q0 + ln) * 64 + g * 8);

    const bf16x8 ones = __builtin_bit_cast(bf16x8,
        make_uint4(0x3F803F80u, 0x3F803F80u, 0x3F803F80u, 0x3F803F80u));

    f32x4v O_[2], lacc;
    const f32x4v zero4 = {0.f, 0.f, 0.f, 0.f};
    O_[0] = zero4; O_[1] = zero4; lacc = zero4;

    const int krow = tid >> 2, ksl = tid & 3;
    const int vrow = tid >> 3, vsl = tid & 7;
    const unsigned short* gk_base = qkrow + (size_t)krow * 64 + 32 + ((ksl ^ ((krow >> 1) & 3)) << 3);
    const unsigned short* gv_base = vb + ((size_t)vrow << 10) + ((vsl ^ (vrow & 7)) << 3);
    const int wbase = w << 9;

#define STAGE_KV(BUF, T0)                                                          \
    {                                                                              \
        __builtin_amdgcn_global_load_lds((const as1_u16*)(gk_base + (size_t)(T0) * 64), \
                                         (as3_u16*)&Ksh[BUF][wbase], 16, 0, 0);    \
        __builtin_amdgcn_global_load_lds((const as1_u16*)(gv_base + (T0)),         \
                                         (as3_u16*)&Vsh[BUF][wbase], 16, 0, 0);    \
    }

    auto compute = [&](int cur) {
        const unsigned short* Kb = &Ksh[cur][0];
        const unsigned short* Vb = &Vsh[cur][0];
        bf16x8 kf_[4], vf_[2][2];
        #pragma unroll
        for (int kf = 0; kf < 4; ++kf)
            kf_[kf] = *(const bf16x8*)(Kb + ((kf * 16 + ln) << 5) + ((g ^ ((ln >> 1) & 3)) << 3));
        #pragma unroll
        for (int df = 0; df < 2; ++df)
            #pragma unroll
            for (int kb = 0; kb < 2; ++kb)
                vf_[df][kb] = *(const bf16x8*)(Vb + ((df * 16 + ln) << 6) + ((((kb << 2) + g) ^ (ln & 7)) << 3));

        f32x4v s_[4];
        __builtin_amdgcn_s_setprio(1);
        #pragma unroll
        for (int kf = 0; kf < 4; ++kf)
            s_[kf] = __builtin_amdgcn_mfma_f32_16x16x32_bf16(kf_[kf], qf_, zero4, 0, 0, 0);
        __builtin_amdgcn_s_setprio(0);

        #pragma unroll
        for (int kf = 0; kf < 4; ++kf)
            #pragma unroll
            for (int r = 0; r < 4; ++r)
                s_[kf][r] = exp2_fast(s_[kf][r]);

        __builtin_amdgcn_s_setprio(1);
        #pragma unroll
        for (int kb = 0; kb < 2; ++kb) {
            unsigned w0 = cvt_pk_bf16(s_[2 * kb][0],     s_[2 * kb][1]);
            unsigned w1 = cvt_pk_bf16(s_[2 * kb][2],     s_[2 * kb][3]);
            unsigned w2 = cvt_pk_bf16(s_[2 * kb + 1][0], s_[2 * kb + 1][1]);
            unsigned w3 = cvt_pk_bf16(s_[2 * kb + 1][2], s_[2 * kb + 1][3]);
            bf16x8 pf = __builtin_bit_cast(bf16x8, make_uint4(w0, w1, w2, w3));
            lacc = __builtin_amdgcn_mfma_f32_16x16x32_bf16(ones, pf, lacc, 0, 0, 0);
            #pragma unroll
            for (int df = 0; df < 2; ++df)
                O_[df] = __builtin_amdgcn_mfma_f32_16x16x32_bf16(vf_[df][kb], pf, O_[df], 0, 0, 0);
        }
        __builtin_amdgcn_s_setprio(0);
    };

    STAGE_KV(0, 0);
    STAGE_KV(1, 64);
    #pragma unroll
    for (int t = 0; t < 14; ++t) {
        STAGE_KV((t + 2) & 3, (t + 2) * 64);
        asm volatile("s_waitcnt vmcnt(4)" ::: "memory");
        __builtin_amdgcn_s_barrier();
        asm volatile("" ::: "memory");
        compute(t & 3);
        asm volatile("" ::: "memory");
    }
    asm volatile("s_waitcnt vmcnt(2)" ::: "memory");
    __builtin_amdgcn_s_barrier();
    asm volatile("" ::: "memory");
    compute(2);
    asm volatile("" ::: "memory");
    asm volatile("s_waitcnt vmcnt(0)" ::: "memory");
    __builtin_amdgcn_s_barrier();
    asm volatile("" ::: "memory");
    compute(3);

    const int b = bh >> 3, n = bh & 7;
    unsigned short* Ab = At + ((size_t)b << 18);
    const float inv = 1.f / lacc[0];
    const int qpos = q0 + ln;
    #pragma unroll
    for (int df = 0; df < 2; ++df) {
        ushort4 pk;
        pk.x = f2bf(O_[df][0] * inv);
        pk.y = f2bf(O_[df][1] * inv);
        pk.z = f2bf(O_[df][2] * inv);
        pk.w = f2bf(O_[df][3] * inv);
        *(ushort4*)(Ab + (size_t)qpos * 256 + n * 32 + df * 16 + g * 4) = pk;
    }
}

// ---------------------------------------------------------------------------
// Out GEMM via MFMA with register prefetch: out = Wo @ At^T + bias + x.
// (unchanged; at its HBM floor ~11 us: mandatory 67 MB x-read + out-write)
// ---------------------------------------------------------------------------
#define OUT_LOAD(WF, AF, KK)                                                        \
    {                                                                               \
        _Pragma("unroll") for (int df = 0; df < 2; ++df)                            \
            WF[df] = *(const bf16x8*)(Wo + (size_t)(ob + df * 16 + ln) * 256 + (KK) + g * 8); \
        _Pragma("unroll") for (int sf = 0; sf < 2; ++sf)                            \
            AF[sf] = *(const bf16x8*)(Ab + (size_t)(sb + sf * 16 + ln) * 256 + (KK) + g * 8); \
    }
#define OUT_MMA(WF, AF)                                                             \
    {                                                                               \
        _Pragma("unroll") for (int df = 0; df < 2; ++df)                            \
            _Pragma("unroll") for (int sf = 0; sf < 2; ++sf)                        \
                acc[df][sf] = __builtin_amdgcn_mfma_f32_16x16x32_bf16(WF[df], AF[sf], acc[df][sf], 0, 0, 0); \
    }

__global__ __launch_bounds__(256) void out_mfma(
    const unsigned short* __restrict__ Wo, const unsigned short* __restrict__ At,
    const float* __restrict__ bias, const float* __restrict__ x,
    float* __restrict__ out)
{
    const int tid = threadIdx.x;
    const int l = tid & 63, w = tid >> 6;
    const int g = l >> 4, ln = l & 15;
    const int b  = blockIdx.z;
    const int ob = blockIdx.y * 32;
    const int sb = blockIdx.x * 128 + w * 32;

    const unsigned short* Ab = At + ((size_t)b << 18);

    f32x4v acc[2][2];
    const f32x4v zero4 = {0.f, 0.f, 0.f, 0.f};
    #pragma unroll
    for (int df = 0; df < 2; ++df)
        #pragma unroll
        for (int sf = 0; sf < 2; ++sf) acc[df][sf] = zero4;

    bf16x8 wA[2], aA[2], wB[2], aB[2];
    OUT_LOAD(wA, aA, 0);
    #pragma unroll
    for (int k0 = 0; k0 < 256; k0 += 64) {
        if (k0 + 32 < 256) OUT_LOAD(wB, aB, k0 + 32);
        OUT_MMA(wA, aA);
        if (k0 + 64 < 256) OUT_LOAD(wA, aA, k0 + 64);
        OUT_MMA(wB, aB);
    }

    #pragma unroll
    for (int df = 0; df < 2; ++df) {
        const float4 b4 = *(const float4*)(bias + ob + df * 16 + g * 4);
        const float bias_r[4] = {b4.x, b4.y, b4.z, b4.w};
        #pragma unroll
        for (int sf = 0; sf < 2; ++sf) {
            const int s = sb + sf * 16 + ln;
            #pragma unroll
            for (int r = 0; r < 4; ++r) {
                const int o = ob + df * 16 + g * 4 + r;
                const size_t idx = ((size_t)b * CIN + o) * SSZ + s;
                out[idx] = acc[df][sf][r] + bias_r[r] + x[idx];
            }
        }
    }
}

// ---------------------------------------------------------------------------
extern "C" void kernel_launch(void* const* d_in, const int* in_sizes, int n_in,
                              void* d_out, int out_size, void* d_ws, size_t ws_size,
                              hipStream_t stream)
{
    const float* x     = (const float*)d_in[0];
    const float* w_qkv = (const float*)d_in[1];
    const float* b_qkv = (const float*)d_in[2];
    const float* w_out = (const float*)d_in[3];
    const float* b_out = (const float*)d_in[4];
    float* out = (float*)d_out;

    // ws (u16 units): qkT 64<<16 | v_buf 64<<15 | At 8<<18 | Wo 65536
    unsigned short* qkT   = (unsigned short*)d_ws;
    unsigned short* v_buf = qkT   + ((size_t)64 << 16);
    unsigned short* At    = v_buf + ((size_t)64 << 15);
    unsigned short* Wo    = At    + ((size_t)8 << 18);

    qkv_fused<<<dim3(8, 9, 8), 256, 0, stream>>>(w_qkv, x, w_out, b_qkv, qkT, v_buf, Wo);
    attn_mfma<<<dim3(64, 16),  256, 0, stream>>>(qkT, v_buf, At);
    out_mfma <<<dim3(8, 8, 8), 256, 0, stream>>>(Wo, At, b_out, x, out);
}

// Round 13
// 49.263 us; speedup vs baseline: 1.0226x; 1.0226x over previous
//
#include <hip/hip_runtime.h>
#include <math.h>

#define BB   8
#define NHD  8
#define SSZ  1024
#define CIN  256
#define HIDC 256

typedef __bf16 bf16_t;
typedef bf16_t bf16x8 __attribute__((ext_vector_type(8)));
typedef float  f32x4v __attribute__((ext_vector_type(4)));

typedef __attribute__((address_space(3))) unsigned short as3_u16;
typedef __attribute__((address_space(1))) unsigned short as1_u16;

__device__ inline unsigned cvt_pk_bf16(float lo, float hi) {
    unsigned r;
    asm("v_cvt_pk_bf16_f32 %0, %1, %2" : "=v"(r) : "v"(lo), "v"(hi));
    return r;
}
__device__ inline unsigned short f2bf(float f) {
    unsigned u = __builtin_bit_cast(unsigned, f);
    u = (u + 0x7fffu + ((u >> 16) & 1u)) >> 16;   // RNE
    return (unsigned short)u;
}
__device__ inline float exp2_fast(float x) {
    float r;
    asm("v_exp_f32 %0, %1" : "=v"(r) : "v"(x));
    return r;
}
__device__ inline int kmap5(int i) {
    return ((i >> 2) & 3) * 8 + ((i >> 4) & 1) * 4 + (i & 3);
}

// ---------------------------------------------------------------------------
// Fused QKV GEMM, BM=96 (one head's q|k|v per block -> 512 blocks = exactly
// 2/CU, perfectly balanced). Per k-half (128c): stage W-half [96o][128c] and
// x-half [128s][128c] f32->bf16 into LDS (coalesced 512B row segments,
// both-sides XOR swizzle cb^(row&15)). 4 waves, each 48o x 64s (3x4 frags).
// blockIdx.y==8 blocks convert w_out f32->bf16 instead.
// Epilogue: bias+SiLU -> slot-permuted qkT / v_buf. Q pre-scaled by
// log2(e)/sqrt(32) for exp2-domain softmax.  [R10 optimum, verbatim]
// ---------------------------------------------------------------------------
#define QKV_LDS_LOAD(WF, XF, KB)                                                    \
    {                                                                               \
        _Pragma("unroll") for (int df = 0; df < 3; ++df) {                          \
            const int orow = (w >> 1) * 48 + df * 16 + ln;                          \
            WF[df] = *(const bf16x8*)(Ws + orow * 128 + ((((KB) + g) ^ (orow & 15)) << 3)); \
        }                                                                           \
        _Pragma("unroll") for (int sf = 0; sf < 4; ++sf) {                          \
            const int srow = sbl + sf * 16 + ln;                                    \
            XF[sf] = *(const bf16x8*)(Xs + srow * 128 + ((((KB) + g) ^ (srow & 15)) << 3)); \
        }                                                                           \
    }
#define QKV_MMA(WF, XF)                                                             \
    {                                                                               \
        _Pragma("unroll") for (int df = 0; df < 3; ++df)                            \
            _Pragma("unroll") for (int sf = 0; sf < 4; ++sf)                        \
                acc[df][sf] = __builtin_amdgcn_mfma_f32_16x16x32_bf16(WF[df], XF[sf], acc[df][sf], 0, 0, 0); \
    }

__global__ __launch_bounds__(256) void qkv_fused(
    const float* __restrict__ W, const float* __restrict__ x,
    const float* __restrict__ w_out, const float* __restrict__ bias,
    unsigned short* __restrict__ qkT, unsigned short* __restrict__ v_buf,
    unsigned short* __restrict__ Wo)
{
    __shared__ unsigned short Ws[96 * 128];    // [o_loc][c_half], swizzled, 24 KB
    __shared__ unsigned short Xs[128 * 128];   // [s_loc][c_half], swizzled, 32 KB

    const int tid = threadIdx.x;

    if (blockIdx.y == 8) {                     // w_out f32 -> bf16 (64 blocks)
        const int chunk = blockIdx.z * 8 + blockIdx.x;        // 0..63
        const size_t idx = (size_t)chunk * 1024 + (size_t)tid * 4;
        float4 v = *(const float4*)(w_out + idx);
        ushort4 pk;
        pk.x = f2bf(v.x); pk.y = f2bf(v.y); pk.z = f2bf(v.z); pk.w = f2bf(v.w);
        *(ushort4*)(Wo + idx) = pk;
        return;
    }

    const int l = tid & 63, w = tid >> 6;
    const int g = l >> 4, ln = l & 15;
    const int b  = blockIdx.z;
    const int head = blockIdx.y;               // one head per block
    const int o0 = head * 96;
    const int ob = o0 + (w >> 1) * 48;
    const int s0 = blockIdx.x * 128;
    const int sbl = (w & 1) * 64;
    const int bh  = b * NHD + head;

    f32x4v acc[3][4];
    const f32x4v zero4 = {0.f, 0.f, 0.f, 0.f};
    #pragma unroll
    for (int df = 0; df < 3; ++df)
        #pragma unroll
        for (int sf = 0; sf < 4; ++sf) acc[df][sf] = zero4;

    bf16x8 wA[3], xA[4], wB[3], xB[4];

    #pragma unroll
    for (int h = 0; h < 2; ++h) {
        if (h) __syncthreads();                // all LDS reads of half 0 done
        // ---- stage W half: 96 rows x 128 c, f32 -> bf16, swizzled ----
        #pragma unroll
        for (int it = 0; it < 12; ++it) {
            const int u   = it * 256 + tid;    // 0..3071
            const int row = u >> 5;            // 0..95
            const int cq  = u & 31;            // float4 within half-row
            const float4 v = *(const float4*)(W + (size_t)(o0 + row) * 256 + h * 128 + cq * 4);
            const int c_loc = cq * 4;
            const int cbp   = ((c_loc >> 3) ^ (row & 15)) << 3;
            unsigned two[2] = { cvt_pk_bf16(v.x, v.y), cvt_pk_bf16(v.z, v.w) };
            *(uint2*)(Ws + row * 128 + cbp + (c_loc & 7)) = *(uint2*)two;
        }
        // ---- stage x half: [s][c] bf16, swizzled ----
        #pragma unroll
        for (int it = 0; it < 8; ++it) {
            const int u  = it * 256 + tid;     // 0..2047
            const int cp = u >> 5;             // 0..63 (c pair)
            const int sq = u & 31;             // s quad
            const float* r0 = x + ((size_t)b * CIN + h * 128 + 2 * cp) * SSZ + s0 + sq * 4;
            const f32x4v a = *(const f32x4v*)r0;
            const f32x4v d = *(const f32x4v*)(r0 + SSZ);
            const int c_loc = 2 * cp;
            const int cb    = c_loc >> 3;
            #pragma unroll
            for (int j = 0; j < 4; ++j) {
                const int s_loc = sq * 4 + j;
                const int elem  = s_loc * 128 + ((cb ^ (s_loc & 15)) << 3) + (c_loc & 7);
                *(unsigned*)(Xs + elem) = cvt_pk_bf16(a[j], d[j]);
            }
        }
        __syncthreads();                       // staging visible

        QKV_LDS_LOAD(wA, xA, 0);
        QKV_LDS_LOAD(wB, xB, 4);
        QKV_MMA(wA, xA);
        QKV_LDS_LOAD(wA, xA, 8);
        QKV_MMA(wB, xB);
        QKV_LDS_LOAD(wB, xB, 12);
        QKV_MMA(wA, xA);
        QKV_MMA(wB, xB);
    }

    #pragma unroll
    for (int df = 0; df < 3; ++df) {
        const int o16  = ob + df * 16;         // stays within one 32-ch part
        const int part = (o16 >> 5) % 3;       // 0=q 1=k 2=v
        const float4 b4 = *(const float4*)(bias + o16 + g * 4);
        const float bias_r[4] = {b4.x, b4.y, b4.z, b4.w};
        const int chb = (o16 & 31) + g * 4;

        float vals[4][4];
        #pragma unroll
        for (int sf = 0; sf < 4; ++sf)
            #pragma unroll
            for (int r = 0; r < 4; ++r) {
                float z = acc[df][sf][r] + bias_r[r];
                z = z / (1.f + __expf(-z));                  // SiLU
                if (part == 0) z *= 0.25503482107810536f;    // log2e/sqrt(32)
                vals[sf][r] = z;
            }

        if (part < 2) {
            const int slotb = ((chb >> 2) & 3) * 8 + ((chb >> 4) & 1) * 4;
            #pragma unroll
            for (int sf = 0; sf < 4; ++sf) {
                const int key = s0 + sbl + sf * 16 + ln;
                ushort4 pk;
                pk.x = f2bf(vals[sf][0]); pk.y = f2bf(vals[sf][1]);
                pk.z = f2bf(vals[sf][2]); pk.w = f2bf(vals[sf][3]);
                *(ushort4*)(qkT + ((size_t)bh << 16) + (size_t)key * 64 + part * 32 + slotb) = pk;
            }
        } else {
            #pragma unroll
            for (int sf = 0; sf < 4; ++sf) {
                const int key  = s0 + sbl + sf * 16 + ln;
                const int koff = (key & ~31) + kmap5(key & 31);
                #pragma unroll
                for (int r = 0; r < 4; ++r)
                    v_buf[((size_t)bh << 15) + ((size_t)(chb + r) << 10) + koff] = f2bf(vals[sf][r]);
            }
        }
    }
}

// ---------------------------------------------------------------------------
// MFMA flash attention, no-max exact softmax, 16 q-rows/wave for 4 waves/SIMD
// occupancy (R10 optimum, verbatim). 4-buffer LDS pipeline, 2 tiles ahead,
// one barrier per tile, counted vmcnt(4). Grid (64 bh, 16 qt).
// ---------------------------------------------------------------------------
__global__ __launch_bounds__(256) void attn_mfma(
    const unsigned short* __restrict__ qkT,
    const unsigned short* __restrict__ v_buf,
    unsigned short* __restrict__ At)
{
    __shared__ unsigned short Ksh[4][2048];
    __shared__ unsigned short Vsh[4][2048];

    const int tid = threadIdx.x;
    const int l   = tid & 63;
    const int w   = tid >> 6;
    const int g   = l >> 4;
    const int ln  = l & 15;
    const int bh  = blockIdx.x;
    const int qt  = blockIdx.y;          // 0..15

    const unsigned short* qkrow = qkT   + ((size_t)bh << 16);
    const unsigned short* vb    = v_buf + ((size_t)bh << 15);

    const int q0 = qt * 64 + w * 16;

    const bf16x8 qf_ = *(const bf16x8*)(qkrow + (size_t)(q0 + ln) * 64 + g * 8);

    const bf16x8 ones = __builtin_bit_cast(bf16x8,
        make_uint4(0x3F803F80u, 0x3F803F80u, 0x3F803F80u, 0x3F803F80u));

    f32x4v O_[2], lacc;
    const f32x4v zero4 = {0.f, 0.f, 0.f, 0.f};
    O_[0] = zero4; O_[1] = zero4; lacc = zero4;

    const int krow = tid >> 2, ksl = tid & 3;
    const int vrow = tid >> 3, vsl = tid & 7;
    const unsigned short* gk_base = qkrow + (size_t)krow * 64 + 32 + ((ksl ^ ((krow >> 1) & 3)) << 3);
    const unsigned short* gv_base = vb + ((size_t)vrow << 10) + ((vsl ^ (vrow & 7)) << 3);
    const int wbase = w << 9;

#define STAGE_KV(BUF, T0)                                                          \
    {                                                                              \
        __builtin_amdgcn_global_load_lds((const as1_u16*)(gk_base + (size_t)(T0) * 64), \
                                         (as3_u16*)&Ksh[BUF][wbase], 16, 0, 0);    \
        __builtin_amdgcn_global_load_lds((const as1_u16*)(gv_base + (T0)),         \
                                         (as3_u16*)&Vsh[BUF][wbase], 16, 0, 0);    \
    }

    auto compute = [&](int cur) {
        const unsigned short* Kb = &Ksh[cur][0];
        const unsigned short* Vb = &Vsh[cur][0];
        bf16x8 kf_[4], vf_[2][2];
        #pragma unroll
        for (int kf = 0; kf < 4; ++kf)
            kf_[kf] = *(const bf16x8*)(Kb + ((kf * 16 + ln) << 5) + ((g ^ ((ln >> 1) & 3)) << 3));
        #pragma unroll
        for (int df = 0; df < 2; ++df)
            #pragma unroll
            for (int kb = 0; kb < 2; ++kb)
                vf_[df][kb] = *(const bf16x8*)(Vb + ((df * 16 + ln) << 6) + ((((kb << 2) + g) ^ (ln & 7)) << 3));

        f32x4v s_[4];
        __builtin_amdgcn_s_setprio(1);
        #pragma unroll
        for (int kf = 0; kf < 4; ++kf)
            s_[kf] = __builtin_amdgcn_mfma_f32_16x16x32_bf16(kf_[kf], qf_, zero4, 0, 0, 0);
        __builtin_amdgcn_s_setprio(0);

        #pragma unroll
        for (int kf = 0; kf < 4; ++kf)
            #pragma unroll
            for (int r = 0; r < 4; ++r)
                s_[kf][r] = exp2_fast(s_[kf][r]);

        __builtin_amdgcn_s_setprio(1);
        #pragma unroll
        for (int kb = 0; kb < 2; ++kb) {
            unsigned w0 = cvt_pk_bf16(s_[2 * kb][0],     s_[2 * kb][1]);
            unsigned w1 = cvt_pk_bf16(s_[2 * kb][2],     s_[2 * kb][3]);
            unsigned w2 = cvt_pk_bf16(s_[2 * kb + 1][0], s_[2 * kb + 1][1]);
            unsigned w3 = cvt_pk_bf16(s_[2 * kb + 1][2], s_[2 * kb + 1][3]);
            bf16x8 pf = __builtin_bit_cast(bf16x8, make_uint4(w0, w1, w2, w3));
            lacc = __builtin_amdgcn_mfma_f32_16x16x32_bf16(ones, pf, lacc, 0, 0, 0);
            #pragma unroll
            for (int df = 0; df < 2; ++df)
                O_[df] = __builtin_amdgcn_mfma_f32_16x16x32_bf16(vf_[df][kb], pf, O_[df], 0, 0, 0);
        }
        __builtin_amdgcn_s_setprio(0);
    };

    STAGE_KV(0, 0);
    STAGE_KV(1, 64);
    #pragma unroll
    for (int t = 0; t < 14; ++t) {
        STAGE_KV((t + 2) & 3, (t + 2) * 64);
        asm volatile("s_waitcnt vmcnt(4)" ::: "memory");
        __builtin_amdgcn_s_barrier();
        asm volatile("" ::: "memory");
        compute(t & 3);
        asm volatile("" ::: "memory");
    }
    asm volatile("s_waitcnt vmcnt(2)" ::: "memory");
    __builtin_amdgcn_s_barrier();
    asm volatile("" ::: "memory");
    compute(2);
    asm volatile("" ::: "memory");
    asm volatile("s_waitcnt vmcnt(0)" ::: "memory");
    __builtin_amdgcn_s_barrier();
    asm volatile("" ::: "memory");
    compute(3);

    const int b = bh >> 3, n = bh & 7;
    unsigned short* Ab = At + ((size_t)b << 18);
    const float inv = 1.f / lacc[0];
    const int qpos = q0 + ln;
    #pragma unroll
    for (int df = 0; df < 2; ++df) {
        ushort4 pk;
        pk.x = f2bf(O_[df][0] * inv);
        pk.y = f2bf(O_[df][1] * inv);
        pk.z = f2bf(O_[df][2] * inv);
        pk.w = f2bf(O_[df][3] * inv);
        *(ushort4*)(Ab + (size_t)qpos * 256 + n * 32 + df * 16 + g * 4) = pk;
    }
}

// ---------------------------------------------------------------------------
// Out GEMM via MFMA with register prefetch: out = Wo @ At^T + bias + x.
// (unchanged; at its HBM floor ~11 us: mandatory 67 MB x-read + out-write)
// ---------------------------------------------------------------------------
#define OUT_LOAD(WF, AF, KK)                                                        \
    {                                                                               \
        _Pragma("unroll") for (int df = 0; df < 2; ++df)                            \
            WF[df] = *(const bf16x8*)(Wo + (size_t)(ob + df * 16 + ln) * 256 + (KK) + g * 8); \
        _Pragma("unroll") for (int sf = 0; sf < 2; ++sf)                            \
            AF[sf] = *(const bf16x8*)(Ab + (size_t)(sb + sf * 16 + ln) * 256 + (KK) + g * 8); \
    }
#define OUT_MMA(WF, AF)                                                             \
    {                                                                               \
        _Pragma("unroll") for (int df = 0; df < 2; ++df)                            \
            _Pragma("unroll") for (int sf = 0; sf < 2; ++sf)                        \
                acc[df][sf] = __builtin_amdgcn_mfma_f32_16x16x32_bf16(WF[df], AF[sf], acc[df][sf], 0, 0, 0); \
    }

__global__ __launch_bounds__(256) void out_mfma(
    const unsigned short* __restrict__ Wo, const unsigned short* __restrict__ At,
    const float* __restrict__ bias, const float* __restrict__ x,
    float* __restrict__ out)
{
    const int tid = threadIdx.x;
    const int l = tid & 63, w = tid >> 6;
    const int g = l >> 4, ln = l & 15;
    const int b  = blockIdx.z;
    const int ob = blockIdx.y * 32;
    const int sb = blockIdx.x * 128 + w * 32;

    const unsigned short* Ab = At + ((size_t)b << 18);

    f32x4v acc[2][2];
    const f32x4v zero4 = {0.f, 0.f, 0.f, 0.f};
    #pragma unroll
    for (int df = 0; df < 2; ++df)
        #pragma unroll
        for (int sf = 0; sf < 2; ++sf) acc[df][sf] = zero4;

    bf16x8 wA[2], aA[2], wB[2], aB[2];
    OUT_LOAD(wA, aA, 0);
    #pragma unroll
    for (int k0 = 0; k0 < 256; k0 += 64) {
        if (k0 + 32 < 256) OUT_LOAD(wB, aB, k0 + 32);
        OUT_MMA(wA, aA);
        if (k0 + 64 < 256) OUT_LOAD(wA, aA, k0 + 64);
        OUT_MMA(wB, aB);
    }

    #pragma unroll
    for (int df = 0; df < 2; ++df) {
        const float4 b4 = *(const float4*)(bias + ob + df * 16 + g * 4);
        const float bias_r[4] = {b4.x, b4.y, b4.z, b4.w};
        #pragma unroll
        for (int sf = 0; sf < 2; ++sf) {
            const int s = sb + sf * 16 + ln;
            #pragma unroll
            for (int r = 0; r < 4; ++r) {
                const int o = ob + df * 16 + g * 4 + r;
                const size_t idx = ((size_t)b * CIN + o) * SSZ + s;
                out[idx] = acc[df][sf][r] + bias_r[r] + x[idx];
            }
        }
    }
}

// ---------------------------------------------------------------------------
extern "C" void kernel_launch(void* const* d_in, const int* in_sizes, int n_in,
                              void* d_out, int out_size, void* d_ws, size_t ws_size,
                              hipStream_t stream)
{
    const float* x     = (const float*)d_in[0];
    const float* w_qkv = (const float*)d_in[1];
    const float* b_qkv = (const float*)d_in[2];
    const float* w_out = (const float*)d_in[3];
    const float* b_out = (const float*)d_in[4];
    float* out = (float*)d_out;

    // ws (u16 units): qkT 64<<16 | v_buf 64<<15 | At 8<<18 | Wo 65536
    unsigned short* qkT   = (unsigned short*)d_ws;
    unsigned short* v_buf = qkT   + ((size_t)64 << 16);
    unsigned short* At    = v_buf + ((size_t)64 << 15);
    unsigned short* Wo    = At    + ((size_t)8 << 18);

    qkv_fused<<<dim3(8, 9, 8), 256, 0, stream>>>(w_qkv, x, w_out, b_qkv, qkT, v_buf, Wo);
    attn_mfma<<<dim3(64, 16),  256, 0, stream>>>(qkT, v_buf, At);
    out_mfma <<<dim3(8, 8, 8), 256, 0, stream>>>(Wo, At, b_out, x, out);
}